// Round 12
// baseline (411.915 us; speedup 1.0000x reference)
//
#include <hip/hip_runtime.h>
#include <stdint.h>

#define GD 128
#define H1 128
#define H2 128
#define NBASES 32
#define NREL 8
#define KZ 1152   // Z width = 8*128 + 128

typedef __attribute__((ext_vector_type(8))) short bf16x8;
typedef __attribute__((ext_vector_type(4))) float f32x4;

static inline size_t align256(size_t x){ return (x + 255) & ~(size_t)255; }

__device__ __forceinline__ float bf2f(uint32_t u16){
  union { uint32_t u; float f; } c; c.u = (u16 & 0xffffu) << 16; return c.f;
}
__device__ __forceinline__ unsigned short f2bf(float f){
  union { float f; uint32_t u; } c; c.f = f;
  uint32_t u = c.u;
  u += 0x7fffu + ((u >> 16) & 1u);   // RTNE (finite inputs)
  return (unsigned short)(u >> 16);
}
__device__ __forceinline__ uint32_t pkbf(float a, float b){
  union { float f; uint32_t u; } ca, cb; ca.f = a; cb.f = b;
  return __builtin_amdgcn_perm(cb.u + 0x8000u, ca.u + 0x8000u, 0x07060302u);
}

__device__ __forceinline__ void async_copy16(void* lds_dst, const void* gsrc){
  __builtin_amdgcn_global_load_lds(
      (const __attribute__((address_space(1))) uint32_t*)gsrc,
      (__attribute__((address_space(3))) uint32_t*)lds_dst, 16, 0, 0);
}

// ==== merged prep: Bz build | B2t build | x cast | xbf pad zero | dst hist ====
__global__ void k_prep(const float* __restrict__ comp, const float* __restrict__ basis,
                       const float* __restrict__ root, unsigned short* __restrict__ Bz,
                       const float* __restrict__ wk, const float* __restrict__ wq,
                       const float* __restrict__ wv, const float* __restrict__ wsk,
                       const float* __restrict__ bk, const float* __restrict__ bq,
                       const float* __restrict__ bv, const float* __restrict__ bs,
                       unsigned short* __restrict__ B2t, float* __restrict__ Bb,
                       const float4* __restrict__ x, uint2* __restrict__ xout, int cnt4,
                       uint32_t* __restrict__ xpadz, int npadz,
                       const int* __restrict__ edst, int* __restrict__ cnt, int E){
  int b = blockIdx.x, t = threadIdx.x;
  if (b < 576){
    // Bz[row=r*128+o][i]: W_r[i,o] (r<8) or root[i,o] (rows 1024..1151)
    int idx = b*256 + t;                 // < 147456 = 1152*128
    int row = idx >> 7, i = idx & 127;
    int r = row >> 7, o = row & 127;
    float v;
    if (r < 8){
      float acc = 0.f;
      #pragma unroll
      for (int bb = 0; bb < NBASES; ++bb)
        acc += comp[r*NBASES + bb] * basis[((size_t)bb*GD + i)*H1 + o];
      v = acc;
    } else {
      v = root[(size_t)i*H1 + o];
    }
    Bz[idx] = f2bf(v);
  } else if (b < 576 + 256){
    int idx = (b - 576)*256 + t;         // < 65536 = 512*H1
    int c = idx / H1, k = idx % H1;
    const float* w = (c < 128) ? wk : (c < 256) ? wq : (c < 384) ? wv : wsk;
    B2t[idx] = f2bf(w[(size_t)k*H2 + (c & 127)]);
    if (idx < 512){
      const float* bia = (idx < 128) ? bk : (idx < 256) ? bq : (idx < 384) ? bv : bs;
      Bb[idx] = bia[idx & 127];
    }
  } else {
    int cb = b - (576 + 256);
    int ncastb = (cnt4 + 255) >> 8;
    if (cb < ncastb){
      int i = cb*256 + t;
      if (i < cnt4){
        float4 v = x[i];
        uint2 o; o.x = pkbf(v.x, v.y); o.y = pkbf(v.z, v.w);
        xout[i] = o;
      }
    } else if (cb < ncastb + 12){
      int i = (cb - ncastb)*256 + t;
      if (i < npadz) xpadz[i] = 0u;      // zero xbf pad rows
    } else {
      int e = (cb - ncastb - 12)*256 + t;
      if (e < E) atomicAdd(&cnt[edst[e]], 1);
    }
  }
}

// ---- single-block exclusive scan over n (shuffle-based, 8/thread) ----
__global__ void k_scan1(const int* __restrict__ deg, int* __restrict__ off,
                        int* __restrict__ cursor, int n, int E){
  __shared__ int wsum[16];
  __shared__ int carry_s;
  int t = threadIdx.x, lane = t & 63, w = t >> 6;
  if (t == 0) carry_s = 0;
  __syncthreads();
  for (int base = 0; base < n; base += 8192){
    int i0 = base + t*8;
    int v[8];
    if (i0 + 7 < n){
      int4 va = *(const int4*)(deg + i0);
      int4 vb = *(const int4*)(deg + i0 + 4);
      v[0]=va.x; v[1]=va.y; v[2]=va.z; v[3]=va.w;
      v[4]=vb.x; v[5]=vb.y; v[6]=vb.z; v[7]=vb.w;
    } else {
      #pragma unroll
      for (int u = 0; u < 8; ++u) v[u] = (i0+u < n) ? deg[i0+u] : 0;
    }
    int s[8]; s[0] = v[0];
    #pragma unroll
    for (int u = 1; u < 8; ++u) s[u] = s[u-1] + v[u];
    int x = s[7];
    #pragma unroll
    for (int d = 1; d < 64; d <<= 1){
      int u = __shfl_up(x, d, 64);
      if (lane >= d) x += u;
    }
    if (lane == 63) wsum[w] = x;
    int carry = carry_s;
    __syncthreads();
    if (t < 16){
      int y = wsum[t];
      #pragma unroll
      for (int d = 1; d < 16; d <<= 1){
        int u = __shfl_up(y, d, 16);
        if (t >= d) y += u;
      }
      wsum[t] = y;
    }
    __syncthreads();
    int woff = (w > 0) ? wsum[w-1] : 0;
    int total = wsum[15];
    int excl = carry + woff + x - s[7];
    #pragma unroll
    for (int u = 0; u < 8; ++u){
      int i = i0 + u;
      if (i < n){ int val = excl + s[u] - v[u]; off[i] = val; cursor[i] = val; }
    }
    __syncthreads();
    if (t == 0) carry_s = carry + total;
    __syncthreads();
  }
  if (t == 0) off[n] = E;
}

// pk[pos] = src | (typ<<20), dst-sorted
__global__ void k_scatter_d(const int* __restrict__ src, const int* __restrict__ dst,
                            const int* __restrict__ typ, int* __restrict__ cursor,
                            int* __restrict__ pk, int E){
  int e = blockIdx.x*blockDim.x + threadIdx.x;
  if (e >= E) return;
  int pos = atomicAdd(&cursor[dst[e]], 1);
  pk[pos] = src[e] | (typ[e] << 20);
}

// ---- zgemm (m97-style): Z(bf16)[npad,1152] = xbf[npad,128] @ Bz^T ----
__launch_bounds__(256)
__global__ void k_zgemm(const unsigned short* __restrict__ A, const unsigned short* __restrict__ Bt,
                        unsigned short* __restrict__ Z){
  __shared__ char lds[16384];
  int t = threadIdx.x, lane = t & 63, wave = t >> 6;
  int row0 = blockIdx.x * 128;
  int c0 = blockIdx.y * 128;
  int mrow = lane & 15, quad = lane >> 4;
  int wrow = (wave & 1) * 64, wcol = (wave >> 1) * 64;
  int s = (mrow >> 1) & 3;

  const unsigned short* Asrc = A + (size_t)(row0 + (t >> 2))*H1 + (((t & 3) ^ ((t >> 3) & 3)) << 3);
  const unsigned short* Bsrc = Bt + (size_t)(c0 + (t >> 2))*H1 + (((t & 3) ^ ((t >> 3) & 3)) << 3);
  char* ldsw = lds + wave*1024;

  int aoff = (wrow + mrow)*64 + ((quad ^ s) << 4);
  int boff = 8192 + (wcol + mrow)*64 + ((quad ^ s) << 4);

  f32x4 acc[4][4];
  #pragma unroll
  for (int i = 0; i < 4; ++i)
    #pragma unroll
    for (int j = 0; j < 4; ++j) acc[i][j] = (f32x4){0.f,0.f,0.f,0.f};

  #pragma unroll
  for (int kt = 0; kt < H1; kt += 32){
    __syncthreads();
    async_copy16(ldsw,         Asrc + kt);
    async_copy16(ldsw + 4096,  Asrc + (size_t)64*H1 + kt);
    async_copy16(ldsw + 8192,  Bsrc + kt);
    async_copy16(ldsw + 12288, Bsrc + (size_t)64*H1 + kt);
    __syncthreads();
    bf16x8 af[4], bf[4];
    #pragma unroll
    for (int i = 0; i < 4; ++i) af[i] = *(const bf16x8*)(lds + aoff + i*1024);
    #pragma unroll
    for (int j = 0; j < 4; ++j) bf[j] = *(const bf16x8*)(lds + boff + j*1024);
    #pragma unroll
    for (int i = 0; i < 4; ++i)
      #pragma unroll
      for (int j = 0; j < 4; ++j)
        acc[i][j] = __builtin_amdgcn_mfma_f32_16x16x32_bf16(af[i], bf[j], acc[i][j], 0, 0, 0);
  }
  #pragma unroll
  for (int j = 0; j < 4; ++j){
    int col = c0 + wcol + j*16 + mrow;
    #pragma unroll
    for (int i = 0; i < 4; ++i)
      #pragma unroll
      for (int rg = 0; rg < 4; ++rg){
        int row = row0 + wrow + i*16 + quad*4 + rg;
        Z[(size_t)row*KZ + col] = f2bf(acc[i][j][rg]);
      }
  }
}

// ---- one wave per dst node: h[d] = sum_e Z[src, rel-block]/cnt_rel + Z[d,root] + bias1.
// dst-sorted pk with rel in bits 20..22; per-rel counts via ballot. ----
__global__ void k_edge1(const int* __restrict__ off_d, const int* __restrict__ pk_d,
                        const unsigned short* __restrict__ Zb,
                        const float* __restrict__ bias1,
                        unsigned short* __restrict__ h, int n, int npad){
  int wid = blockIdx.x*(blockDim.x >> 6) + (threadIdx.x >> 6);
  int lane = threadIdx.x & 63;
  if (wid >= npad) return;
  uint32_t* hrow = (uint32_t*)(h + (size_t)wid*H1);
  if (wid >= n){ hrow[lane] = 0u; return; }
  const uint32_t* Z32 = (const uint32_t*)Zb;
  int ov = off_d[wid + (lane & 1)];
  int o = __builtin_amdgcn_readlane(ov, 0);
  int dg = __builtin_amdgcn_readlane(ov, 1) - o;

  float a0 = 0.f, a1 = 0.f;
  if (dg <= 64){
    int m = dg;
    int pj = (lane < m) ? pk_d[o + lane] : 0;
    int rel = (pj >> 20) & 7;
    int cr[8];
    #pragma unroll
    for (int r = 0; r < 8; ++r)
      cr[r] = __popcll(__ballot(lane < m && rel == r));
    float inv[8];
    #pragma unroll
    for (int r = 0; r < 8; ++r) inv[r] = (cr[r] > 0) ? 1.f/(float)cr[r] : 0.f;
    float wv = inv[0];
    #pragma unroll
    for (int r = 1; r < 8; ++r) wv = (rel == r) ? inv[r] : wv;
    int gidx = (pj & 0xFFFFF)*(KZ/2) + rel*64;
    int jj = 0;
    for (; jj + 8 <= m; jj += 8){
      uint32_t g[8]; float wgt[8];
      #pragma unroll
      for (int k = 0; k < 8; ++k){
        int gx = __builtin_amdgcn_readlane(gidx, jj + k);
        wgt[k] = __int_as_float(__builtin_amdgcn_readlane(__float_as_int(wv), jj + k));
        g[k] = Z32[(size_t)(uint32_t)gx + lane];
      }
      #pragma unroll
      for (int k = 0; k < 8; ++k){
        a0 += bf2f(g[k]) * wgt[k];
        a1 += bf2f(g[k] >> 16) * wgt[k];
      }
    }
    for (; jj + 4 <= m; jj += 4){
      uint32_t g[4]; float wgt[4];
      #pragma unroll
      for (int k = 0; k < 4; ++k){
        int gx = __builtin_amdgcn_readlane(gidx, jj + k);
        wgt[k] = __int_as_float(__builtin_amdgcn_readlane(__float_as_int(wv), jj + k));
        g[k] = Z32[(size_t)(uint32_t)gx + lane];
      }
      #pragma unroll
      for (int k = 0; k < 4; ++k){
        a0 += bf2f(g[k]) * wgt[k];
        a1 += bf2f(g[k] >> 16) * wgt[k];
      }
    }
    for (; jj < m; ++jj){
      int gx = __builtin_amdgcn_readlane(gidx, jj);
      float wg = __int_as_float(__builtin_amdgcn_readlane(__float_as_int(wv), jj));
      uint32_t gg = Z32[(size_t)(uint32_t)gx + lane];
      a0 += bf2f(gg) * wg;
      a1 += bf2f(gg >> 16) * wg;
    }
  } else {
    // rare high-degree path: two chunked passes (count, then accumulate)
    int cr[8];
    #pragma unroll
    for (int r = 0; r < 8; ++r) cr[r] = 0;
    for (int jb = 0; jb < dg; jb += 64){
      int m = dg - jb; if (m > 64) m = 64;
      int pj = (lane < m) ? pk_d[o + jb + lane] : 0;
      int rel = (pj >> 20) & 7;
      #pragma unroll
      for (int r = 0; r < 8; ++r)
        cr[r] += __popcll(__ballot(lane < m && rel == r));
    }
    float inv[8];
    #pragma unroll
    for (int r = 0; r < 8; ++r) inv[r] = (cr[r] > 0) ? 1.f/(float)cr[r] : 0.f;
    for (int jb = 0; jb < dg; jb += 64){
      int m = dg - jb; if (m > 64) m = 64;
      int pj = (lane < m) ? pk_d[o + jb + lane] : 0;
      int rel = (pj >> 20) & 7;
      float wv = inv[0];
      #pragma unroll
      for (int r = 1; r < 8; ++r) wv = (rel == r) ? inv[r] : wv;
      int gidx = (pj & 0xFFFFF)*(KZ/2) + rel*64;
      int jj = 0;
      for (; jj + 8 <= m; jj += 8){
        uint32_t g[8]; float wgt[8];
        #pragma unroll
        for (int k = 0; k < 8; ++k){
          int gx = __builtin_amdgcn_readlane(gidx, jj + k);
          wgt[k] = __int_as_float(__builtin_amdgcn_readlane(__float_as_int(wv), jj + k));
          g[k] = Z32[(size_t)(uint32_t)gx + lane];
        }
        #pragma unroll
        for (int k = 0; k < 8; ++k){
          a0 += bf2f(g[k]) * wgt[k];
          a1 += bf2f(g[k] >> 16) * wgt[k];
        }
      }
      for (; jj < m; ++jj){
        int gx = __builtin_amdgcn_readlane(gidx, jj);
        float wg = __int_as_float(__builtin_amdgcn_readlane(__float_as_int(wv), jj));
        uint32_t gg = Z32[(size_t)(uint32_t)gx + lane];
        a0 += bf2f(gg) * wg;
        a1 += bf2f(gg >> 16) * wg;
      }
    }
  }
  uint32_t zr = Z32[(size_t)wid*(KZ/2) + 512 + lane];
  float2 bb = ((const float2*)bias1)[lane];
  hrow[lane] = pkbf(a0 + bf2f(zr) + bb.x, a1 + bf2f(zr >> 16) + bb.y);
}

// ---- GEMM2 (m97-style): [npad,512] = h @ B2t^T + Bb; skip -> skipb(bf16) ----
__launch_bounds__(256)
__global__ void k_gemm2(const unsigned short* __restrict__ A, const unsigned short* __restrict__ Bt,
                        const float* __restrict__ Bb, unsigned short* __restrict__ kqv,
                        unsigned short* __restrict__ skipb, int n){
  __shared__ char lds[16384];
  int t = threadIdx.x, lane = t & 63, wave = t >> 6;
  int row0 = blockIdx.x * 128;
  int c0 = blockIdx.y * 128;
  int mrow = lane & 15, quad = lane >> 4;
  int wrow = (wave & 1) * 64, wcol = (wave >> 1) * 64;
  int s = (mrow >> 1) & 3;

  const unsigned short* Asrc = A + (size_t)(row0 + (t >> 2))*H1 + (((t & 3) ^ ((t >> 3) & 3)) << 3);
  const unsigned short* Bsrc = Bt + (size_t)(c0 + (t >> 2))*H1 + (((t & 3) ^ ((t >> 3) & 3)) << 3);
  char* ldsw = lds + wave*1024;

  int aoff = (wrow + mrow)*64 + ((quad ^ s) << 4);
  int boff = 8192 + (wcol + mrow)*64 + ((quad ^ s) << 4);

  f32x4 acc[4][4];
  #pragma unroll
  for (int i = 0; i < 4; ++i)
    #pragma unroll
    for (int j = 0; j < 4; ++j) acc[i][j] = (f32x4){0.f,0.f,0.f,0.f};

  #pragma unroll
  for (int kt = 0; kt < H1; kt += 32){
    __syncthreads();
    async_copy16(ldsw,         Asrc + kt);
    async_copy16(ldsw + 4096,  Asrc + (size_t)64*H1 + kt);
    async_copy16(ldsw + 8192,  Bsrc + kt);
    async_copy16(ldsw + 12288, Bsrc + (size_t)64*H1 + kt);
    __syncthreads();
    bf16x8 af[4], bf[4];
    #pragma unroll
    for (int i = 0; i < 4; ++i) af[i] = *(const bf16x8*)(lds + aoff + i*1024);
    #pragma unroll
    for (int j = 0; j < 4; ++j) bf[j] = *(const bf16x8*)(lds + boff + j*1024);
    #pragma unroll
    for (int i = 0; i < 4; ++i)
      #pragma unroll
      for (int j = 0; j < 4; ++j)
        acc[i][j] = __builtin_amdgcn_mfma_f32_16x16x32_bf16(af[i], bf[j], acc[i][j], 0, 0, 0);
  }
  #pragma unroll
  for (int j = 0; j < 4; ++j){
    int col = c0 + wcol + j*16 + mrow;
    float bcol = Bb[col];
    #pragma unroll
    for (int i = 0; i < 4; ++i)
      #pragma unroll
      for (int rg = 0; rg < 4; ++rg){
        int rr = row0 + wrow + i*16 + quad*4 + rg;
        if (rr >= n) continue;
        float v = acc[i][j][rg] + bcol;
        if (col < 128){
          kqv[(size_t)rr*384 + col] = f2bf(v);
        } else if (col < 256){
          int jj = col - 128;
          kqv[(size_t)rr*384 + 128 + ((jj >> 1) << 2) + (jj & 1)] = f2bf(v);
        } else if (col < 384){
          int jj = col - 256;
          kqv[(size_t)rr*384 + 128 + ((jj >> 1) << 2) + 2 + (jj & 1)] = f2bf(v);
        } else {
          skipb[(size_t)rr*H2 + (col - 384)] = f2bf(v);
        }
      }
  }
}

// ---- one wave per dst node: out = sum_e sigmoid(k+q)*v + skip (pure write) ----
__global__ void k_edge2(const int* __restrict__ off_d, const int* __restrict__ pk_d,
                        const unsigned short* __restrict__ kqv,
                        const unsigned short* __restrict__ skipb,
                        float* __restrict__ out, int n){
  int wid = blockIdx.x*(blockDim.x >> 6) + (threadIdx.x >> 6);
  int lane = threadIdx.x & 63;
  if (wid >= n) return;
  const uint32_t* kv32 = (const uint32_t*)kqv;
  int ov = off_d[wid + (lane & 1)];
  int o = __builtin_amdgcn_readlane(ov, 0);
  int dg = __builtin_amdgcn_readlane(ov, 1) - o;

  uint32_t ku = kv32[(size_t)wid*192 + lane];
  float k0 = bf2f(ku), k1 = bf2f(ku >> 16);
  float a0 = 0.f, a1 = 0.f;
  for (int jb = 0; jb < dg; jb += 64){
    int m = dg - jb; if (m > 64) m = 64;
    int pj = (lane < m) ? pk_d[o + jb + lane] : 0;
    int jj = 0;
    for (; jj + 8 <= m; jj += 8){
      uint2 q[8];
      #pragma unroll
      for (int k = 0; k < 8; ++k){
        int s = __builtin_amdgcn_readlane(pj, jj + k) & 0xFFFFF;
        q[k] = *(const uint2*)(kv32 + (size_t)s*192 + 64 + lane*2);
      }
      #pragma unroll
      for (int k = 0; k < 8; ++k){
        float qq0 = bf2f(q[k].x), qq1 = bf2f(q[k].x >> 16);
        float vv0 = bf2f(q[k].y), vv1 = bf2f(q[k].y >> 16);
        float g0 = 1.f / (1.f + __expf(-(k0 + qq0)));
        float g1 = 1.f / (1.f + __expf(-(k1 + qq1)));
        a0 += g0*vv0; a1 += g1*vv1;
      }
    }
    for (; jj + 4 <= m; jj += 4){
      uint2 q[4];
      #pragma unroll
      for (int k = 0; k < 4; ++k){
        int s = __builtin_amdgcn_readlane(pj, jj + k) & 0xFFFFF;
        q[k] = *(const uint2*)(kv32 + (size_t)s*192 + 64 + lane*2);
      }
      #pragma unroll
      for (int k = 0; k < 4; ++k){
        float qq0 = bf2f(q[k].x), qq1 = bf2f(q[k].x >> 16);
        float vv0 = bf2f(q[k].y), vv1 = bf2f(q[k].y >> 16);
        float g0 = 1.f / (1.f + __expf(-(k0 + qq0)));
        float g1 = 1.f / (1.f + __expf(-(k1 + qq1)));
        a0 += g0*vv0; a1 += g1*vv1;
      }
    }
    for (; jj < m; ++jj){
      int s = __builtin_amdgcn_readlane(pj, jj) & 0xFFFFF;
      uint2 qc = *(const uint2*)(kv32 + (size_t)s*192 + 64 + lane*2);
      float qq0 = bf2f(qc.x), qq1 = bf2f(qc.x >> 16);
      float vv0 = bf2f(qc.y), vv1 = bf2f(qc.y >> 16);
      float g0 = 1.f / (1.f + __expf(-(k0 + qq0)));
      float g1 = 1.f / (1.f + __expf(-(k1 + qq1)));
      a0 += g0*vv0; a1 += g1*vv1;
    }
  }
  uint32_t sk = ((const uint32_t*)skipb)[(size_t)wid*64 + lane];
  float2 cur; cur.x = a0 + bf2f(sk); cur.y = a1 + bf2f(sk >> 16);
  ((float2*)(out + (size_t)wid*H2))[lane] = cur;
}

extern "C" void kernel_launch(void* const* d_in, const int* in_sizes, int n_in,
                              void* d_out, int out_size, void* d_ws, size_t ws_size,
                              hipStream_t stream){
  const float* x     = (const float*)d_in[0];
  const int*   eidx  = (const int*)  d_in[1];
  const int*   etype = (const int*)  d_in[3];
  const float* basis = (const float*)d_in[4];
  const float* comp  = (const float*)d_in[5];
  const float* root  = (const float*)d_in[6];
  const float* bias1 = (const float*)d_in[7];
  const float* wk    = (const float*)d_in[8];
  const float* bk    = (const float*)d_in[9];
  const float* wq    = (const float*)d_in[10];
  const float* bq    = (const float*)d_in[11];
  const float* wv    = (const float*)d_in[12];
  const float* bv    = (const float*)d_in[13];
  const float* wsk   = (const float*)d_in[14];
  const float* bs    = (const float*)d_in[15];
  const int n = in_sizes[0] / GD;          // 50000
  const int E = in_sizes[3];               // 600000
  const int npad = (n + 127) & ~127;       // 50048
  const int* esrc = eidx;
  const int* edst = eidx + E;
  float* out = (float*)d_out;

  char* w = (char*)d_ws;
  size_t off = 0;
  unsigned short* xbf  = (unsigned short*)(w + off); off = align256(off + (size_t)npad*GD*2);
  unsigned short* Zbuf = (unsigned short*)(w + off); off = align256(off + (size_t)npad*KZ*2);
  unsigned short* Bz   = (unsigned short*)(w + off); off = align256(off + (size_t)KZ*H1*2);
  unsigned short* B2t  = (unsigned short*)(w + off); off = align256(off + (size_t)512*H1*2);
  float* Bb            = (float*)(w + off);          off = align256(off + 512*4);
  unsigned short* hbuf = (unsigned short*)(w + off); off = align256(off + (size_t)npad*H1*2);
  unsigned short* kqv  = (unsigned short*)(w + off); off = align256(off + (size_t)n*384*2);
  unsigned short* skipb= (unsigned short*)(w + off); off = align256(off + (size_t)npad*H2*2);
  int* cnt_d           = (int*)(w + off);            off = align256(off + (size_t)(n+4)*4);
  int* off_d           = (int*)(w + off);            off = align256(off + (size_t)(n+1)*4);
  int* cur_d           = (int*)(w + off);            off = align256(off + (size_t)n*4);
  int* pk_d            = (int*)(w + off);            off = align256(off + (size_t)E*4);

  const int cnt4 = n*GD/4;                       // 1.6M
  const int ncastb = (cnt4 + 255)/256;           // 6250
  const int histb  = (E + 255)/256;              // 2344
  const int npadz  = (npad - n)*GD/2;            // pad uint32 count

  hipMemsetAsync(cnt_d, 0, (size_t)n*4, stream);

  k_prep<<<576 + 256 + ncastb + 12 + histb, 256, 0, stream>>>(
      comp, basis, root, Bz, wk, wq, wv, wsk, bk, bq, bv, bs, B2t, Bb,
      (const float4*)x, (uint2*)xbf, cnt4,
      (uint32_t*)(xbf + (size_t)n*GD), npadz,
      edst, cnt_d, E);
  k_scan1<<<1, 1024, 0, stream>>>(cnt_d, off_d, cur_d, n, E);
  k_scatter_d<<<(E + 255)/256, 256, 0, stream>>>(esrc, edst, etype, cur_d, pk_d, E);
  k_zgemm<<<dim3(npad/128, KZ/128), 256, 0, stream>>>(xbf, Bz, Zbuf);
  k_edge1<<<(npad + 3)/4, 256, 0, stream>>>(off_d, pk_d, Zbuf, bias1, hbuf, n, npad);
  k_gemm2<<<dim3(npad/128, 4), 256, 0, stream>>>(hbuf, B2t, Bb, kqv, skipb, n);
  k_edge2<<<(n + 3)/4, 256, 0, stream>>>(off_d, pk_d, kqv, skipb, out, n);
}